// Round 3
// baseline (265.706 us; speedup 1.0000x reference)
//
#include <hip/hip_runtime.h>

namespace {

constexpr int B  = 128;
constexpr int A  = 8732;
constexpr int NC = 21;
constexpr int THREADS = 256;
constexpr int ABLK = (A + THREADS - 1) / THREADS;  // 35 blocks per row

__device__ __forceinline__ float waveReduceSum(float v) {
#pragma unroll
    for (int off = 32; off; off >>= 1) v += __shfl_xor(v, off, 64);
    return v;
}
__device__ __forceinline__ int waveReduceSumI(int v) {
#pragma unroll
    for (int off = 32; off; off >>= 1) v += __shfl_xor(v, off, 64);
    return v;
}

// ws layout: acc[0]=loc_loss, acc[1]=cls_loss ; npos[B] per-row positive counts
__global__ void init_kernel(float* __restrict__ acc, int* __restrict__ npos) {
    int t = threadIdx.x;
    if (t < 2) acc[t] = 0.f;
    if (t < B) npos[t] = 0;
}

__global__ __launch_bounds__(THREADS) void main_kernel(
    const float* __restrict__ locp,
    const float* __restrict__ loct,
    const float* __restrict__ clsp,
    const int*   __restrict__ tgt,
    float* __restrict__ acc,
    int*   __restrict__ npos)
{
    const int b  = blockIdx.y;
    const int a0 = blockIdx.x * THREADS;
    const int rem = (A - a0 < THREADS) ? (A - a0) : THREADS;  // 256 or 28; both %4==0

    // ---- stage cls tile: coalesced float4 global -> LDS ----
    // base offset (b*A + a0)*21 floats is always 16B-aligned (rem%4==0, A*21*4%16==0... b*A*21=183372*b, *4B %16==0; a0*21*4=21504*bx %16==0)
    __shared__ float scls[THREADS * NC];  // 21504 B
    {
        const float4* __restrict__ src = (const float4*)(clsp + ((long)b * A + a0) * NC);
        float4* __restrict__ dst = (float4*)scls;
        const int nf4 = rem * NC / 4;  // 1344 or 147
        for (int k = threadIdx.x; k < nf4; k += THREADS) dst[k] = src[k];
    }
    __syncthreads();

    float ce = 0.f, locv = 0.f;
    int posc = 0;

    if (threadIdx.x < rem) {
        const long i = (long)b * A + (a0 + threadIdx.x);
        const int t = tgt[i];

        // ---- cross entropy from LDS: ce = logsumexp(x) - x[tgt] ----
        const float* __restrict__ x = scls + threadIdx.x * NC;  // stride 21 (odd) -> 2-way bank alias, free
        float xs[NC];
#pragma unroll
        for (int c = 0; c < NC; ++c) xs[c] = x[c];
        float m = xs[0];
#pragma unroll
        for (int c = 1; c < NC; ++c) m = fmaxf(m, xs[c]);
        float s = 0.f;
#pragma unroll
        for (int c = 0; c < NC; ++c) s += __expf(xs[c] - m);
        const int tc = t < 0 ? 0 : (t > NC - 1 ? NC - 1 : t);
        ce = (t < 0) ? 0.f : (m + __logf(s) - xs[tc]);

        // ---- masked smooth-L1 over 4 coords (already coalesced float4) ----
        if (t > 0) {
            posc = 1;
            const float4 lp = *(const float4*)(locp + i * 4);
            const float4 lt = *(const float4*)(loct + i * 4);
            float d;
            d = fabsf(lp.x - lt.x); locv += (d < 1.f) ? 0.5f * d * d : d - 0.5f;
            d = fabsf(lp.y - lt.y); locv += (d < 1.f) ? 0.5f * d * d : d - 0.5f;
            d = fabsf(lp.z - lt.z); locv += (d < 1.f) ? 0.5f * d * d : d - 0.5f;
            d = fabsf(lp.w - lt.w); locv += (d < 1.f) ? 0.5f * d * d : d - 0.5f;
        }
    }

    // block reduction (4 waves of 64)
    __shared__ float sLoc[4], sCls[4];
    __shared__ int sPos[4];
    const int wid = threadIdx.x >> 6, lane = threadIdx.x & 63;
    float wl = waveReduceSum(locv);
    float wc = waveReduceSum(ce);
    int   wp = waveReduceSumI(posc);
    if (lane == 0) { sLoc[wid] = wl; sCls[wid] = wc; sPos[wid] = wp; }
    __syncthreads();
    if (threadIdx.x == 0) {
        float L = sLoc[0] + sLoc[1] + sLoc[2] + sLoc[3];
        float C = sCls[0] + sCls[1] + sCls[2] + sCls[3];
        int   P = sPos[0] + sPos[1] + sPos[2] + sPos[3];
        atomicAdd(&acc[0], L);
        atomicAdd(&acc[1], C);   // optimistic: sum of ALL ce (all-selected fast path)
        atomicAdd(&npos[b], P);
    }
}

// Correction for rows where hard-negative mining actually excludes anchors
// (3*num_pos < A). For the reference input distribution this never triggers
// (P(pos) = 20/21 -> 3*num_pos ~ 25k >> 8732), but keep it for correctness.
__global__ __launch_bounds__(THREADS) void mining_kernel(
    const float* __restrict__ clsp,
    const int*   __restrict__ tgt,
    const int*   __restrict__ npos,
    float* __restrict__ acc)
{
    const int b = blockIdx.x;
    const int K = 3 * npos[b];
    if (K >= A) return;  // everything selected; main_kernel's sum is exact

    __shared__ float mined[A];  // 34.9 KB
    for (int i = threadIdx.x; i < A; i += THREADS) {
        const long idx = (long)b * A + i;
        const int t = tgt[idx];
        float ce = 0.f;
        if (t >= 0) {
            const float* __restrict__ x = clsp + idx * (long)NC;
            float m = x[0];
            for (int c = 1; c < NC; ++c) m = fmaxf(m, x[c]);
            float s = 0.f;
            for (int c = 0; c < NC; ++c) s += __expf(x[c] - m);
            const int tc = t > NC - 1 ? NC - 1 : t;
            ce = m + __logf(s) - x[tc];
        }
        mined[i] = (t > 0) ? 0.f : -ce;  // matches ce*(pos-1)
    }
    __syncthreads();

    float corr = 0.f;  // subtract ce of unselected anchors
    for (int i = threadIdx.x; i < A; i += THREADS) {
        const int t = tgt[(long)b * A + i];
        if (t > 0) continue;  // positives always selected
        const float mi = mined[i];
        int rank = 0;  // stable-sort rank: #{j: key_j < key_i} with (value, idx) lex order
        for (int j = 0; j < A; ++j) {
            const float mj = mined[j];
            rank += (mj < mi || (mj == mi && j < i)) ? 1 : 0;
        }
        if (rank >= K) corr += mi;  // mi = -ce_i
    }

    __shared__ float sC[4];
    const int wid = threadIdx.x >> 6, lane = threadIdx.x & 63;
    float wcorr = waveReduceSum(corr);
    if (lane == 0) sC[wid] = wcorr;
    __syncthreads();
    if (threadIdx.x == 0) atomicAdd(&acc[1], sC[0] + sC[1] + sC[2] + sC[3]);
}

__global__ void finalize_kernel(const float* __restrict__ acc,
                                const int* __restrict__ npos,
                                float* __restrict__ out)
{
    if (threadIdx.x == 0) {
        int np = 0;
        for (int i = 0; i < B; ++i) np += npos[i];
        out[0] = (acc[0] + acc[1]) / (float)np;
    }
}

}  // namespace

extern "C" void kernel_launch(void* const* d_in, const int* in_sizes, int n_in,
                              void* d_out, int out_size, void* d_ws, size_t ws_size,
                              hipStream_t stream) {
    const float* locp = (const float*)d_in[0];
    const float* loct = (const float*)d_in[1];
    const float* clsp = (const float*)d_in[2];
    const int*   tgt  = (const int*)d_in[3];

    float* acc  = (float*)d_ws;
    int*   npos = (int*)((char*)d_ws + 2 * sizeof(float));
    float* out  = (float*)d_out;

    hipLaunchKernelGGL(init_kernel, dim3(1), dim3(256), 0, stream, acc, npos);
    hipLaunchKernelGGL(main_kernel, dim3(ABLK, B), dim3(THREADS), 0, stream,
                       locp, loct, clsp, tgt, acc, npos);
    hipLaunchKernelGGL(mining_kernel, dim3(B), dim3(THREADS), 0, stream,
                       clsp, tgt, npos, acc);
    hipLaunchKernelGGL(finalize_kernel, dim3(1), dim3(64), 0, stream, acc, npos, out);
}

// Round 4
// 182.594 us; speedup vs baseline: 1.4552x; 1.4552x over previous
//
#include <hip/hip_runtime.h>

namespace {

constexpr int B  = 128;
constexpr int A  = 8732;
constexpr int NC = 21;
constexpr int THREADS = 256;
constexpr int ABLK = (A + THREADS - 1) / THREADS;  // 35 blocks per row
constexpr int NBLK = ABLK * B;                     // 4480 partial slots

__device__ __forceinline__ float waveReduceSum(float v) {
#pragma unroll
    for (int off = 32; off; off >>= 1) v += __shfl_xor(v, off, 64);
    return v;
}
__device__ __forceinline__ int waveReduceSumI(int v) {
#pragma unroll
    for (int off = 32; off; off >>= 1) v += __shfl_xor(v, off, 64);
    return v;
}

// ws layout (all written unconditionally every launch; no init kernel needed):
//   float locPart[NBLK]; float clsPart[NBLK]; int posPart[NBLK]; float corr[B]
__global__ __launch_bounds__(THREADS) void main_kernel(
    const float* __restrict__ locp,
    const float* __restrict__ loct,
    const float* __restrict__ clsp,
    const int*   __restrict__ tgt,
    float* __restrict__ locPart,
    float* __restrict__ clsPart,
    int*   __restrict__ posPart)
{
    const int b  = blockIdx.y;
    const int a0 = blockIdx.x * THREADS;
    const int rem = (A - a0 < THREADS) ? (A - a0) : THREADS;  // 256 or 28; both %4==0

    // ---- stage cls tile: coalesced float4 global -> LDS ----
    __shared__ float scls[THREADS * NC];  // 21504 B
    {
        const float4* __restrict__ src = (const float4*)(clsp + ((long)b * A + a0) * NC);
        float4* __restrict__ dst = (float4*)scls;
        const int nf4 = rem * NC / 4;  // 1344 or 147
        for (int k = threadIdx.x; k < nf4; k += THREADS) dst[k] = src[k];
    }
    __syncthreads();

    float ce = 0.f, locv = 0.f;
    int posc = 0;

    if (threadIdx.x < rem) {
        const long i = (long)b * A + (a0 + threadIdx.x);
        const int t = tgt[i];

        // ---- cross entropy from LDS: ce = logsumexp(x) - x[tgt] ----
        const float* __restrict__ x = scls + threadIdx.x * NC;  // stride 21: 2-way bank alias, free
        float xs[NC];
#pragma unroll
        for (int c = 0; c < NC; ++c) xs[c] = x[c];
        float m = xs[0];
#pragma unroll
        for (int c = 1; c < NC; ++c) m = fmaxf(m, xs[c]);
        float s = 0.f;
#pragma unroll
        for (int c = 0; c < NC; ++c) s += __expf(xs[c] - m);
        const int tc = t < 0 ? 0 : (t > NC - 1 ? NC - 1 : t);
        ce = (t < 0) ? 0.f : (m + __logf(s) - xs[tc]);

        // ---- masked smooth-L1 over 4 coords (coalesced float4) ----
        if (t > 0) {
            posc = 1;
            const float4 lp = *(const float4*)(locp + i * 4);
            const float4 lt = *(const float4*)(loct + i * 4);
            float d;
            d = fabsf(lp.x - lt.x); locv += (d < 1.f) ? 0.5f * d * d : d - 0.5f;
            d = fabsf(lp.y - lt.y); locv += (d < 1.f) ? 0.5f * d * d : d - 0.5f;
            d = fabsf(lp.z - lt.z); locv += (d < 1.f) ? 0.5f * d * d : d - 0.5f;
            d = fabsf(lp.w - lt.w); locv += (d < 1.f) ? 0.5f * d * d : d - 0.5f;
        }
    }

    // block reduction (4 waves of 64)
    __shared__ float sLoc[4], sCls[4];
    __shared__ int sPos[4];
    const int wid = threadIdx.x >> 6, lane = threadIdx.x & 63;
    float wl = waveReduceSum(locv);
    float wc = waveReduceSum(ce);
    int   wp = waveReduceSumI(posc);
    if (lane == 0) { sLoc[wid] = wl; sCls[wid] = wc; sPos[wid] = wp; }
    __syncthreads();
    if (threadIdx.x == 0) {
        const int blk = b * gridDim.x + blockIdx.x;
        locPart[blk] = sLoc[0] + sLoc[1] + sLoc[2] + sLoc[3];
        clsPart[blk] = sCls[0] + sCls[1] + sCls[2] + sCls[3];   // sum of ALL ce (all-selected fast path)
        posPart[blk] = sPos[0] + sPos[1] + sPos[2] + sPos[3];
    }
}

// Correction for rows where hard-negative mining actually excludes anchors
// (3*num_pos < A). Never triggers for the reference distribution
// (P(pos)=20/21 -> 3*num_pos ~ 25k >> 8732); kept for general correctness.
// Self-contained: counts its own row's positives; writes corr[b] (0 fast path).
__global__ __launch_bounds__(THREADS) void mining_kernel(
    const float* __restrict__ clsp,
    const int*   __restrict__ tgt,
    float* __restrict__ corr)
{
    const int b = blockIdx.x;
    const int wid = threadIdx.x >> 6, lane = threadIdx.x & 63;

    // count positives in this row (coalesced int reads)
    int cnt = 0;
    for (int i = threadIdx.x; i < A; i += THREADS) cnt += (tgt[(long)b * A + i] > 0) ? 1 : 0;
    __shared__ int sCnt[4];
    int wcnt = waveReduceSumI(cnt);
    if (lane == 0) sCnt[wid] = wcnt;
    __syncthreads();
    const int K = 3 * (sCnt[0] + sCnt[1] + sCnt[2] + sCnt[3]);  // block-uniform

    float corrv = 0.f;
    if (K < A) {  // block-uniform branch; __syncthreads inside is safe
        __shared__ float mined[A];  // 34.9 KB
        for (int i = threadIdx.x; i < A; i += THREADS) {
            const long idx = (long)b * A + i;
            const int t = tgt[idx];
            float ce = 0.f;
            if (t >= 0) {
                const float* __restrict__ x = clsp + idx * (long)NC;
                float m = x[0];
                for (int c = 1; c < NC; ++c) m = fmaxf(m, x[c]);
                float s = 0.f;
                for (int c = 0; c < NC; ++c) s += __expf(x[c] - m);
                const int tc = t > NC - 1 ? NC - 1 : t;
                ce = m + __logf(s) - x[tc];
            }
            mined[i] = (t > 0) ? 0.f : -ce;  // matches ce*(pos-1)
        }
        __syncthreads();

        float c0 = 0.f;  // sum of mi (= -ce) over unselected anchors
        for (int i = threadIdx.x; i < A; i += THREADS) {
            const int t = tgt[(long)b * A + i];
            if (t > 0) continue;  // positives always selected
            const float mi = mined[i];
            int rank = 0;  // stable-sort rank with (value, idx) lex order
            for (int j = 0; j < A; ++j) {
                const float mj = mined[j];
                rank += (mj < mi || (mj == mi && j < i)) ? 1 : 0;
            }
            if (rank >= K) c0 += mi;
        }
        __shared__ float sC[4];
        float wcorr = waveReduceSum(c0);
        if (lane == 0) sC[wid] = wcorr;
        __syncthreads();
        corrv = sC[0] + sC[1] + sC[2] + sC[3];
    }
    if (threadIdx.x == 0) corr[b] = corrv;  // unconditional write (0 fast path)
}

__global__ __launch_bounds__(THREADS) void finalize_kernel(
    const float* __restrict__ locPart,
    const float* __restrict__ clsPart,
    const int*   __restrict__ posPart,
    const float* __restrict__ corr,
    float* __restrict__ out)
{
    float L = 0.f, C = 0.f;
    int P = 0;
    for (int i = threadIdx.x; i < NBLK; i += THREADS) {
        L += locPart[i];
        C += clsPart[i];
        P += posPart[i];
    }
    if (threadIdx.x < B) C += corr[threadIdx.x];

    __shared__ float sL[4], sC[4];
    __shared__ int sP[4];
    const int wid = threadIdx.x >> 6, lane = threadIdx.x & 63;
    float wl = waveReduceSum(L);
    float wc = waveReduceSum(C);
    int   wp = waveReduceSumI(P);
    if (lane == 0) { sL[wid] = wl; sC[wid] = wc; sP[wid] = wp; }
    __syncthreads();
    if (threadIdx.x == 0) {
        const float loc = sL[0] + sL[1] + sL[2] + sL[3];
        const float cls = sC[0] + sC[1] + sC[2] + sC[3];
        const int   np  = sP[0] + sP[1] + sP[2] + sP[3];
        out[0] = (loc + cls) / (float)np;
    }
}

}  // namespace

extern "C" void kernel_launch(void* const* d_in, const int* in_sizes, int n_in,
                              void* d_out, int out_size, void* d_ws, size_t ws_size,
                              hipStream_t stream) {
    const float* locp = (const float*)d_in[0];
    const float* loct = (const float*)d_in[1];
    const float* clsp = (const float*)d_in[2];
    const int*   tgt  = (const int*)d_in[3];

    float* locPart = (float*)d_ws;
    float* clsPart = locPart + NBLK;
    int*   posPart = (int*)(clsPart + NBLK);
    float* corr    = (float*)(posPart + NBLK);
    float* out     = (float*)d_out;

    hipLaunchKernelGGL(main_kernel, dim3(ABLK, B), dim3(THREADS), 0, stream,
                       locp, loct, clsp, tgt, locPart, clsPart, posPart);
    hipLaunchKernelGGL(mining_kernel, dim3(B), dim3(THREADS), 0, stream,
                       clsp, tgt, corr);
    hipLaunchKernelGGL(finalize_kernel, dim3(1), dim3(THREADS), 0, stream,
                       locPart, clsPart, posPart, corr, out);
}

// Round 5
// 180.657 us; speedup vs baseline: 1.4708x; 1.0107x over previous
//
#include <hip/hip_runtime.h>
#include <stdint.h>

namespace {

constexpr int B  = 128;
constexpr int A  = 8732;
constexpr int NC = 21;
constexpr int THREADS = 256;
constexpr int ABLK = (A + THREADS - 1) / THREADS;  // 35 blocks per row
constexpr int NBLK = ABLK * B;                     // 4480 partial slots

__device__ __forceinline__ float waveReduceSum(float v) {
#pragma unroll
    for (int off = 32; off; off >>= 1) v += __shfl_xor(v, off, 64);
    return v;
}
__device__ __forceinline__ int waveReduceSumI(int v) {
#pragma unroll
    for (int off = 32; off; off >>= 1) v += __shfl_xor(v, off, 64);
    return v;
}

// ws layout: float locPart[NBLK]; float clsPart[NBLK]; int posPart[NBLK]; float corr[B]
__global__ __launch_bounds__(THREADS) void main_kernel(
    const float* __restrict__ locp,
    const float* __restrict__ loct,
    const float* __restrict__ clsp,
    const int*   __restrict__ tgt,
    float* __restrict__ locPart,
    float* __restrict__ clsPart,
    int*   __restrict__ posPart)
{
    const int b  = blockIdx.y;
    const int a0 = blockIdx.x * THREADS;
    const int rem = (A - a0 < THREADS) ? (A - a0) : THREADS;  // 256 or 28; both %4==0
    const int lane = threadIdx.x & 63;

    // ---- stage cls tile: async HBM->LDS DMA (global_load_lds, 16B/lane) ----
    // LDS dest is wave-uniform base + lane*16: (idx - lane) is wave-uniform, layout linear.
    // Global base is float4-aligned: (b*A+a0)*21*4 = b*733488 + bx*21504, both %16==0.
    __shared__ __align__(16) float scls[THREADS * NC];  // 21504 B
    {
        const float4* __restrict__ src = (const float4*)(clsp + ((long)b * A + a0) * NC);
        const int nf4 = rem * NC / 4;  // 1344 or 147
        for (int idx = threadIdx.x; idx < nf4; idx += THREADS) {
            __builtin_amdgcn_global_load_lds(
                (const __attribute__((address_space(1))) void*)(src + idx),
                (__attribute__((address_space(3))) void*)(scls + (idx - lane) * 4),
                16, 0, 0);
        }
    }

    // ---- issue tgt + loc loads now so they overlap the staging DMA ----
    int t = 0;
    float4 lp = make_float4(0.f, 0.f, 0.f, 0.f);
    float4 lt = make_float4(0.f, 0.f, 0.f, 0.f);
    const long i = (long)b * A + (a0 + threadIdx.x);
    if (threadIdx.x < rem) {
        t  = tgt[i];
        lp = *(const float4*)(locp + i * 4);
        lt = *(const float4*)(loct + i * 4);
    }

    __syncthreads();  // compiler emits s_waitcnt vmcnt(0) before s_barrier -> DMA complete

    float ce = 0.f, locv = 0.f;
    int posc = 0;

    if (threadIdx.x < rem) {
        // ---- cross entropy from LDS: ce = logsumexp(x) - x[tgt] ----
        const float* __restrict__ x = scls + threadIdx.x * NC;  // stride 21: 2-way bank alias, free
        float xs[NC];
#pragma unroll
        for (int c = 0; c < NC; ++c) xs[c] = x[c];
        float m = xs[0];
#pragma unroll
        for (int c = 1; c < NC; ++c) m = fmaxf(m, xs[c]);
        float s = 0.f;
#pragma unroll
        for (int c = 0; c < NC; ++c) s += __expf(xs[c] - m);
        const int tc = t < 0 ? 0 : (t > NC - 1 ? NC - 1 : t);
        ce = (t < 0) ? 0.f : (m + __logf(s) - xs[tc]);

        // ---- masked smooth-L1 over 4 coords ----
        if (t > 0) {
            posc = 1;
            float d;
            d = fabsf(lp.x - lt.x); locv += (d < 1.f) ? 0.5f * d * d : d - 0.5f;
            d = fabsf(lp.y - lt.y); locv += (d < 1.f) ? 0.5f * d * d : d - 0.5f;
            d = fabsf(lp.z - lt.z); locv += (d < 1.f) ? 0.5f * d * d : d - 0.5f;
            d = fabsf(lp.w - lt.w); locv += (d < 1.f) ? 0.5f * d * d : d - 0.5f;
        }
    }

    // block reduction (4 waves of 64)
    __shared__ float sLoc[4], sCls[4];
    __shared__ int sPos[4];
    const int wid = threadIdx.x >> 6;
    float wl = waveReduceSum(locv);
    float wc = waveReduceSum(ce);
    int   wp = waveReduceSumI(posc);
    if (lane == 0) { sLoc[wid] = wl; sCls[wid] = wc; sPos[wid] = wp; }
    __syncthreads();
    if (threadIdx.x == 0) {
        const int blk = b * gridDim.x + blockIdx.x;
        locPart[blk] = sLoc[0] + sLoc[1] + sLoc[2] + sLoc[3];
        clsPart[blk] = sCls[0] + sCls[1] + sCls[2] + sCls[3];   // sum of ALL ce (all-selected fast path)
        posPart[blk] = sPos[0] + sPos[1] + sPos[2] + sPos[3];
    }
}

// Correction for rows where hard-negative mining actually excludes anchors
// (3*num_pos < A). Never triggers for the reference distribution
// (P(pos)=20/21 -> 3*num_pos ~ 25k >> 8732); kept for general correctness.
// Fast path reads main_kernel's per-block pos counts (35 ints) instead of 8732 tgt.
__global__ __launch_bounds__(THREADS) void mining_kernel(
    const float* __restrict__ clsp,
    const int*   __restrict__ tgt,
    const int*   __restrict__ posPart,
    float* __restrict__ corr)
{
    const int b = blockIdx.x;
    const int wid = threadIdx.x >> 6, lane = threadIdx.x & 63;

    int cnt = (threadIdx.x < ABLK) ? posPart[b * ABLK + threadIdx.x] : 0;
    __shared__ int sCnt[4];
    int wcnt = waveReduceSumI(cnt);
    if (lane == 0) sCnt[wid] = wcnt;
    __syncthreads();
    const int K = 3 * (sCnt[0] + sCnt[1] + sCnt[2] + sCnt[3]);  // block-uniform

    float corrv = 0.f;
    if (K < A) {  // block-uniform branch; __syncthreads inside is safe
        __shared__ float mined[A];  // 34.9 KB
        for (int i = threadIdx.x; i < A; i += THREADS) {
            const long idx = (long)b * A + i;
            const int t = tgt[idx];
            float ce = 0.f;
            if (t >= 0) {
                const float* __restrict__ x = clsp + idx * (long)NC;
                float m = x[0];
                for (int c = 1; c < NC; ++c) m = fmaxf(m, x[c]);
                float s = 0.f;
                for (int c = 0; c < NC; ++c) s += __expf(x[c] - m);
                const int tc = t > NC - 1 ? NC - 1 : t;
                ce = m + __logf(s) - x[tc];
            }
            mined[i] = (t > 0) ? 0.f : -ce;  // matches ce*(pos-1)
        }
        __syncthreads();

        float c0 = 0.f;  // sum of mi (= -ce) over unselected anchors
        for (int i = threadIdx.x; i < A; i += THREADS) {
            const int t = tgt[(long)b * A + i];
            if (t > 0) continue;  // positives always selected
            const float mi = mined[i];
            int rank = 0;  // stable-sort rank with (value, idx) lex order
            for (int j = 0; j < A; ++j) {
                const float mj = mined[j];
                rank += (mj < mi || (mj == mi && j < i)) ? 1 : 0;
            }
            if (rank >= K) c0 += mi;
        }
        __shared__ float sC[4];
        float wcorr = waveReduceSum(c0);
        if (lane == 0) sC[wid] = wcorr;
        __syncthreads();
        corrv = sC[0] + sC[1] + sC[2] + sC[3];
    }
    if (threadIdx.x == 0) corr[b] = corrv;  // unconditional write (0 fast path)
}

__global__ __launch_bounds__(THREADS) void finalize_kernel(
    const float* __restrict__ locPart,
    const float* __restrict__ clsPart,
    const int*   __restrict__ posPart,
    const float* __restrict__ corr,
    float* __restrict__ out)
{
    float L = 0.f, C = 0.f;
    int P = 0;
    for (int i = threadIdx.x; i < NBLK; i += THREADS) {
        L += locPart[i];
        C += clsPart[i];
        P += posPart[i];
    }
    if (threadIdx.x < B) C += corr[threadIdx.x];

    __shared__ float sL[4], sC[4];
    __shared__ int sP[4];
    const int wid = threadIdx.x >> 6, lane = threadIdx.x & 63;
    float wl = waveReduceSum(L);
    float wc = waveReduceSum(C);
    int   wp = waveReduceSumI(P);
    if (lane == 0) { sL[wid] = wl; sC[wid] = wc; sP[wid] = wp; }
    __syncthreads();
    if (threadIdx.x == 0) {
        const float loc = sL[0] + sL[1] + sL[2] + sL[3];
        const float cls = sC[0] + sC[1] + sC[2] + sC[3];
        const int   np  = sP[0] + sP[1] + sP[2] + sP[3];
        out[0] = (loc + cls) / (float)np;
    }
}

}  // namespace

extern "C" void kernel_launch(void* const* d_in, const int* in_sizes, int n_in,
                              void* d_out, int out_size, void* d_ws, size_t ws_size,
                              hipStream_t stream) {
    const float* locp = (const float*)d_in[0];
    const float* loct = (const float*)d_in[1];
    const float* clsp = (const float*)d_in[2];
    const int*   tgt  = (const int*)d_in[3];

    float* locPart = (float*)d_ws;
    float* clsPart = locPart + NBLK;
    int*   posPart = (int*)(clsPart + NBLK);
    float* corr    = (float*)(posPart + NBLK);
    float* out     = (float*)d_out;

    hipLaunchKernelGGL(main_kernel, dim3(ABLK, B), dim3(THREADS), 0, stream,
                       locp, loct, clsp, tgt, locPart, clsPart, posPart);
    hipLaunchKernelGGL(mining_kernel, dim3(B), dim3(THREADS), 0, stream,
                       clsp, tgt, posPart, corr);
    hipLaunchKernelGGL(finalize_kernel, dim3(1), dim3(THREADS), 0, stream,
                       locPart, clsPart, posPart, corr, out);
}